// Round 7
// baseline (1234.909 us; speedup 1.0000x reference)
//
#include <hip/hip_runtime.h>
#include <math.h>

#define B 8
#define C 64
#define L 2048
#define CS 256
#define BCL  (B*C*L)    // 1048576
#define BCSL (B*CS*L)   // 4194304
#define HS 0.25f

typedef unsigned short u16;
typedef unsigned int   u32;
typedef __attribute__((ext_vector_type(8))) short sh8;
typedef __attribute__((ext_vector_type(4))) float f4;
typedef __attribute__((ext_vector_type(8))) unsigned short us8;
typedef __attribute__((ext_vector_type(4))) unsigned short us4;

__device__ __forceinline__ float gelu(float x) {
    return 0.5f * x * (1.0f + erff(x * 0.70710678118654752440f));
}
__device__ __forceinline__ u16 f2b(float f) {
    u32 u = __float_as_uint(f);
    u32 r = u + 0x7FFFu + ((u >> 16) & 1u);
    return (u16)(r >> 16);
}
__device__ __forceinline__ float b2f(u16 h) {
    return __uint_as_float(((u32)h) << 16);
}

// ---------- weight prep: fp32 [oc][ic][k] -> bf16 A-frag order ----------
__global__ __launch_bounds__(256) void prep_k(const float* __restrict__ w,
        u16* __restrict__ dst, int IC, int OC) {
    int idx = blockIdx.x * 256 + threadIdx.x;
    int OCG = OC >> 4;
    int j = idx & 7, lane = (idx >> 3) & 63, t = idx >> 9;
    int ocg = t % OCG, c = t / OCG;
    int oc = ocg * 16 + (lane & 15);
    int K = c * 32 + ((lane >> 4) & 3) * 8 + j;
    int kk = K / IC, ic = K % IC;
    dst[idx] = f2b(w[((size_t)oc * IC + ic) * 3 + kk]);
}

// ---------- all 25 cond vectors ----------
__global__ void cond25_k(const float* __restrict__ tw1, const float* __restrict__ tb1,
                         const float* __restrict__ tw2, const float* __restrict__ tb2,
                         const float* __restrict__ cw, const float* __restrict__ cb,
                         float* __restrict__ condall) {
    __shared__ float te1[16], te2[16];
    int tix = blockIdx.x;
    int tid = threadIdx.x;
    double add[6] = {0.0, 0.25/5.0, 3.0*0.25/10.0, 4.0*0.25/5.0, 8.0*0.25/9.0, 0.25};
    float t = (tix == 24) ? 1.0f : (float)((double)(tix / 6) * 0.25 + add[tix % 6]);
    if (tid < 16) te1[tid] = gelu(t * tw1[tid] + tb1[tid]);
    __syncthreads();
    if (tid < 16) {
        float s = tb2[tid];
        for (int k = 0; k < 16; ++k) s += te1[k] * tw2[tid*16+k];
        te2[tid] = s;
    }
    __syncthreads();
    float s = cb[tid];
    for (int j = 0; j < 16; ++j) s += te2[j] * cw[tid*16+j];
    condall[tix*128 + tid] = s;
}

// ======================================================================
// Whole-RK-step fused kernel.
// 16-pos output tiles; unified r-coordinate: global pos = l0 - 18 + r.
// y staged 52 rows; s1..s5 live only in LDS (rows 46,40,34,28,22 at
// offsets 3,6,9,12,15); stage-6 output rows [18,34) = [l0, l0+16).
// conv alignment: output row r reads input rows r-1+kk, kk=0..2.
// ======================================================================

template<int K, int STEP>
__device__ __forceinline__ void do_stage(int tid, int l0, int b,
    const u16* __restrict__ wp1, const float* __restrict__ kb1,
    const u16* __restrict__ wp2, const float* __restrict__ kb2,
    const u16* __restrict__ wp3, const float* __restrict__ kb3,
    const float* __restrict__ condall,
    u16 (&ybt)[52][264], u16 (&xs)[52][264],
    u16 (&s1t)[46][264], u16 (&s2t)[40][264], u16 (&s3t)[34][264],
    u16 (&s4t)[28][264], u16 (&s5t)[22][264],
    u16 (&h1)[52][72], u16 (&h2)[52][72],
    float* __restrict__ ytr, u16* __restrict__ ybo, float* __restrict__ outp)
{
    constexpr int OFF = 3 * K;
    constexpr int N   = 52 - 6 * K;
    constexpr int NF1 = (N + 4 + 15) / 16;
    constexpr int NF2 = (N + 2 + 15) / 16;
    constexpr int NF3 = (N + 15) / 16;
    const int wave = tid >> 6, lane = tid & 63;
    const int nlo = lane & 15, quad = lane >> 4;

    // ---- combo -> xs (K>=2); K==1 uses ybt directly ----
    if (K >= 2) {
        const float a1 = HS * (K==2 ? 1.f/5.f : K==3 ? 3.f/40.f : K==4 ? 44.f/45.f :
                               K==5 ? 19372.f/6561.f : 9017.f/3168.f);
        const float a2 = HS * (K==3 ? 9.f/40.f : K==4 ? -56.f/15.f :
                               K==5 ? -25360.f/2187.f : -355.f/33.f);
        const float a3 = HS * (K==4 ? 32.f/9.f : K==5 ? 64448.f/6561.f : 46732.f/5247.f);
        const float a4 = HS * (K==5 ? -212.f/729.f : 49.f/176.f);
        const float a5 = HS * (-5103.f/18656.f);
        constexpr int rows = N + 6, base = OFF - 3, items = rows * 32;
        #pragma unroll
        for (int it = 0; it < (items + 255) / 256; ++it) {
            int idx = it * 256 + tid;
            if (idx < items) {
                int r = base + (idx >> 5), co = (idx & 31) * 8;
                float f[8];
                us8 v = *(const us8*)&ybt[r][co];
                #pragma unroll
                for (int j = 0; j < 8; ++j) f[j] = b2f(v[j]);
                { us8 w = *(const us8*)&s1t[r-3][co];
                  #pragma unroll
                  for (int j = 0; j < 8; ++j) f[j] += a1 * b2f(w[j]); }
                if (K >= 3) { us8 w = *(const us8*)&s2t[r-6][co];
                  #pragma unroll
                  for (int j = 0; j < 8; ++j) f[j] += a2 * b2f(w[j]); }
                if (K >= 4) { us8 w = *(const us8*)&s3t[r-9][co];
                  #pragma unroll
                  for (int j = 0; j < 8; ++j) f[j] += a3 * b2f(w[j]); }
                if (K >= 5) { us8 w = *(const us8*)&s4t[r-12][co];
                  #pragma unroll
                  for (int j = 0; j < 8; ++j) f[j] += a4 * b2f(w[j]); }
                if (K >= 6) { us8 w = *(const us8*)&s5t[r-15][co];
                  #pragma unroll
                  for (int j = 0; j < 8; ++j) f[j] += a5 * b2f(w[j]); }
                us8 o;
                #pragma unroll
                for (int j = 0; j < 8; ++j) o[j] = f2b(f[j]);
                *(us8*)&xs[r][co] = o;
            }
        }
        __syncthreads();
    }
    u16 (&xq)[52][264] = (K == 1) ? ybt : xs;

    // ---- conv1: M=64 (16/wave), FiLM+GELU -> h1 rows [OFF-2, OFF+N+2) ----
    {
        f4 acc[NF1];
        #pragma unroll
        for (int j = 0; j < NF1; ++j) acc[j] = f4{0.f,0.f,0.f,0.f};
        const sh8* w1 = (const sh8*)wp1;
        for (int c = 0; c < 24; ++c) {
            int kk = c >> 3, ic0 = (c & 7) << 5;
            sh8 A = w1[(c*4 + wave)*64 + lane];
            #pragma unroll
            for (int j = 0; j < NF1; ++j) {
                int row = OFF - 3 + 16*j + nlo + kk;
                row = row > 51 ? 51 : row;
                sh8 Bv = *(const sh8*)&xq[row][ic0 + quad*8];
                acc[j] = __builtin_amdgcn_mfma_f32_16x16x32_bf16(A, Bv, acc[j], 0, 0, 0);
            }
        }
        const float* cd = condall + (STEP*6 + (K-1))*128;
        #pragma unroll
        for (int j = 0; j < NF1; ++j) {
            int p = OFF - 2 + 16*j + nlo;
            if (p < 52) {
                int gp = l0 - 18 + p;
                bool ok = (p < OFF + N + 2) && (gp >= 0) && (gp < L);
                #pragma unroll
                for (int reg = 0; reg < 4; ++reg) {
                    int oc = wave*16 + quad*4 + reg;
                    float v = (1.f + cd[oc]) * (acc[j][reg] + kb1[oc]) + cd[64+oc];
                    h1[p][oc] = ok ? f2b(gelu(v)) : (u16)0;
                }
            }
        }
    }
    __syncthreads();

    // ---- conv2: GELU -> h2 rows [OFF-1, OFF+N+1) ----
    {
        f4 acc[NF2];
        #pragma unroll
        for (int j = 0; j < NF2; ++j) acc[j] = f4{0.f,0.f,0.f,0.f};
        const sh8* w2 = (const sh8*)wp2;
        #pragma unroll
        for (int c = 0; c < 6; ++c) {
            int kk = c >> 1, ic0 = (c & 1) << 5;
            sh8 A = w2[(c*4 + wave)*64 + lane];
            #pragma unroll
            for (int j = 0; j < NF2; ++j) {
                int row = OFF - 2 + 16*j + nlo + kk;
                row = row > 51 ? 51 : row;
                sh8 Bv = *(const sh8*)&h1[row][ic0 + quad*8];
                acc[j] = __builtin_amdgcn_mfma_f32_16x16x32_bf16(A, Bv, acc[j], 0, 0, 0);
            }
        }
        #pragma unroll
        for (int j = 0; j < NF2; ++j) {
            int q = OFF - 1 + 16*j + nlo;
            if (q < 52) {
                int gq = l0 - 18 + q;
                bool ok = (q < OFF + N + 1) && (gq >= 0) && (gq < L);
                #pragma unroll
                for (int reg = 0; reg < 4; ++reg) {
                    int oc = wave*16 + quad*4 + reg;
                    h2[q][oc] = ok ? f2b(gelu(acc[j][reg] + kb2[oc])) : (u16)0;
                }
            }
        }
    }
    __syncthreads();

    // ---- conv3: M=256 (4 mf/wave) -> sK rows [OFF, OFF+N) or y-update ----
    f4 acc[NF3][4];
    #pragma unroll
    for (int j = 0; j < NF3; ++j)
        #pragma unroll
        for (int mf = 0; mf < 4; ++mf) acc[j][mf] = f4{0.f,0.f,0.f,0.f};
    {
        const sh8* w3 = (const sh8*)wp3;
        #pragma unroll
        for (int c = 0; c < 6; ++c) {
            int kk = c >> 1, ic0 = (c & 1) << 5;
            #pragma unroll
            for (int j = 0; j < NF3; ++j) {
                int row = OFF - 1 + 16*j + nlo + kk;
                row = row > 51 ? 51 : row;
                sh8 Bv = *(const sh8*)&h2[row][ic0 + quad*8];
                #pragma unroll
                for (int mf = 0; mf < 4; ++mf) {
                    sh8 A = w3[(c*16 + wave*4 + mf)*64 + lane];
                    acc[j][mf] = __builtin_amdgcn_mfma_f32_16x16x32_bf16(A, Bv, acc[j][mf], 0, 0, 0);
                }
            }
        }
    }

    if (K < 6) {
        #pragma unroll
        for (int j = 0; j < NF3; ++j) {
            int p = OFF + 16*j + nlo;
            if (p < OFF + N) {
                int gp = l0 - 18 + p;
                bool ok = (gp >= 0) && (gp < L);
                #pragma unroll
                for (int mf = 0; mf < 4; ++mf) {
                    int baseoc = (wave*4 + mf)*16 + quad*4;
                    us4 pk;
                    #pragma unroll
                    for (int reg = 0; reg < 4; ++reg) {
                        float v = acc[j][mf][reg] + kb3[baseoc + reg];
                        pk[reg] = ok ? f2b(v) : (u16)0;
                    }
                    if (K == 1) *(us4*)&s1t[p-OFF][baseoc] = pk;
                    if (K == 2) *(us4*)&s2t[p-OFF][baseoc] = pk;
                    if (K == 3) *(us4*)&s3t[p-OFF][baseoc] = pk;
                    if (K == 4) *(us4*)&s4t[p-OFF][baseoc] = pk;
                    if (K == 5) *(us4*)&s5t[p-OFF][baseoc] = pk;
                }
            }
        }
        __syncthreads();
    } else {
        // y-update: rows [18,34) = positions [l0, l0+16)
        const float cy1 = HS*(35.f/384.f), cy3 = HS*(500.f/1113.f),
                    cy4 = HS*(125.f/192.f), cy5 = -HS*(2187.f/6784.f),
                    cy6 = HS*(11.f/84.f);
        int p = 18 + nlo;
        int gp = l0 + nlo;
        #pragma unroll
        for (int mf = 0; mf < 4; ++mf) {
            int baseoc = (wave*4 + mf)*16 + quad*4;
            size_t ta = ((size_t)b * L + gp) * 256 + baseoc;
            us4 v1 = *(const us4*)&s1t[p-3][baseoc];
            us4 v3 = *(const us4*)&s3t[p-9][baseoc];
            us4 v4 = *(const us4*)&s4t[p-12][baseoc];
            us4 v5 = *(const us4*)&s5t[p-15][baseoc];
            f4 y4 = *(const f4*)(ytr + ta);
            us4 pk; f4 yo;
            #pragma unroll
            for (int reg = 0; reg < 4; ++reg) {
                int oc = baseoc + reg;
                float s6 = acc[0][mf][reg] + kb3[oc];
                float yv = y4[reg] + cy1*b2f(v1[reg]) + cy3*b2f(v3[reg])
                         + cy4*b2f(v4[reg]) + cy5*b2f(v5[reg]) + cy6*s6;
                yo[reg] = yv;
                pk[reg] = f2b(yv);
                if (STEP == 3) {
                    outp[(((size_t)(oc >> 6)*B + b)*64 + (oc & 63))*L + gp] = yv;
                }
            }
            if (STEP < 3) *(f4*)(ytr + ta) = yo;
            *(us4*)(ybo + ta) = pk;
        }
    }
}

template<int STEP>
__global__ __launch_bounds__(256, 1) void rkstep_k(
    const u16* __restrict__ wp1, const float* __restrict__ kb1,
    const u16* __restrict__ wp2, const float* __restrict__ kb2,
    const u16* __restrict__ wp3, const float* __restrict__ kb3,
    const float* __restrict__ condall,
    float* __restrict__ ytr, const u16* __restrict__ ybi,
    u16* __restrict__ ybo, float* __restrict__ outp)
{
    __shared__ u16 ybt[52][264], xs[52][264];
    __shared__ u16 s1t[46][264], s2t[40][264], s3t[34][264], s4t[28][264], s5t[22][264];
    __shared__ u16 h1[52][72], h2[52][72];
    const int tid = threadIdx.x;
    const int bx = blockIdx.x;
    const int tile = ((bx & 7) << 4) | (bx >> 3);   // XCD swizzle
    const int l0 = tile * 16;
    const int b = blockIdx.y;

    // stage yb halo: rows 0..51, pos = l0-18+r
    #pragma unroll
    for (int it = 0; it < 7; ++it) {
        int idx = it * 256 + tid;
        if (idx < 52 * 32) {
            int r = idx >> 5, co = (idx & 31) * 8;
            int gl = l0 - 18 + r;
            us8 v = {};
            if (gl >= 0 && gl < L) v = *(const us8*)(ybi + ((size_t)b*L + gl)*256 + co);
            *(us8*)&ybt[r][co] = v;
        }
    }
    __syncthreads();

    do_stage<1,STEP>(tid, l0, b, wp1,kb1,wp2,kb2,wp3,kb3, condall,
                     ybt, xs, s1t,s2t,s3t,s4t,s5t, h1,h2, ytr, ybo, outp);
    do_stage<2,STEP>(tid, l0, b, wp1,kb1,wp2,kb2,wp3,kb3, condall,
                     ybt, xs, s1t,s2t,s3t,s4t,s5t, h1,h2, ytr, ybo, outp);
    do_stage<3,STEP>(tid, l0, b, wp1,kb1,wp2,kb2,wp3,kb3, condall,
                     ybt, xs, s1t,s2t,s3t,s4t,s5t, h1,h2, ytr, ybo, outp);
    do_stage<4,STEP>(tid, l0, b, wp1,kb1,wp2,kb2,wp3,kb3, condall,
                     ybt, xs, s1t,s2t,s3t,s4t,s5t, h1,h2, ytr, ybo, outp);
    do_stage<5,STEP>(tid, l0, b, wp1,kb1,wp2,kb2,wp3,kb3, condall,
                     ybt, xs, s1t,s2t,s3t,s4t,s5t, h1,h2, ytr, ybo, outp);
    do_stage<6,STEP>(tid, l0, b, wp1,kb1,wp2,kb2,wp3,kb3, condall,
                     ybt, xs, s1t,s2t,s3t,s4t,s5t, h1,h2, ytr, ybo, outp);
}

// ---------- final dx = ode_f(1.0, y) + ecloss (dx never stored) ----------
__global__ __launch_bounds__(256) void dxec_k(
    const u16* __restrict__ ybi,
    const u16* __restrict__ wp1, const float* __restrict__ kb1,
    const u16* __restrict__ wp2, const float* __restrict__ kb2,
    const u16* __restrict__ wp3, const float* __restrict__ kb3,
    const float* __restrict__ condall,
    const float* __restrict__ stacked, double* __restrict__ inner)
{
    __shared__ u16 xs[22][264];
    __shared__ u16 h1[22][72];
    __shared__ u16 h2[20][72];
    __shared__ double sred[4];
    const int tid = threadIdx.x;
    const int bx = blockIdx.x;
    const int tile = ((bx & 7) << 4) | (bx >> 3);
    const int l0 = tile * 16;
    const int b = blockIdx.y;

    #pragma unroll
    for (int it = 0; it < 3; ++it) {
        int idx = it * 256 + tid;
        if (idx < 22 * 32) {
            int r = idx >> 5, co = (idx & 31) * 8;
            int gl = l0 - 3 + r;
            us8 v = {};
            if (gl >= 0 && gl < L) v = *(const us8*)(ybi + ((size_t)b*L + gl)*256 + co);
            *(us8*)&xs[r][co] = v;
        }
    }
    __syncthreads();

    const int wave = tid >> 6, lane = tid & 63;
    const int nlo = lane & 15, quad = lane >> 4;

    // conv1 -> h1 rows [1,21)
    {
        f4 acc[2];
        acc[0] = f4{0.f,0.f,0.f,0.f}; acc[1] = acc[0];
        const sh8* w1 = (const sh8*)wp1;
        for (int c = 0; c < 24; ++c) {
            int kk = c >> 3, ic0 = (c & 7) << 5;
            sh8 A = w1[(c*4 + wave)*64 + lane];
            #pragma unroll
            for (int j = 0; j < 2; ++j) {
                int row = 16*j + nlo + kk;
                row = row > 21 ? 21 : row;
                sh8 Bv = *(const sh8*)&xs[row][ic0 + quad*8];
                acc[j] = __builtin_amdgcn_mfma_f32_16x16x32_bf16(A, Bv, acc[j], 0, 0, 0);
            }
        }
        const float* cd = condall + 24*128;
        #pragma unroll
        for (int j = 0; j < 2; ++j) {
            int p = 1 + 16*j + nlo;
            if (p < 22) {
                int gp = l0 - 3 + p;
                bool ok = (p < 21) && (gp >= 0) && (gp < L);
                #pragma unroll
                for (int reg = 0; reg < 4; ++reg) {
                    int oc = wave*16 + quad*4 + reg;
                    float v = (1.f + cd[oc]) * (acc[j][reg] + kb1[oc]) + cd[64+oc];
                    h1[p][oc] = ok ? f2b(gelu(v)) : (u16)0;
                }
            }
        }
    }
    __syncthreads();

    // conv2 -> h2 rows [2,20)
    {
        f4 acc[2];
        acc[0] = f4{0.f,0.f,0.f,0.f}; acc[1] = acc[0];
        const sh8* w2 = (const sh8*)wp2;
        #pragma unroll
        for (int c = 0; c < 6; ++c) {
            int kk = c >> 1, ic0 = (c & 1) << 5;
            sh8 A = w2[(c*4 + wave)*64 + lane];
            #pragma unroll
            for (int j = 0; j < 2; ++j) {
                int row = 1 + 16*j + nlo + kk;
                row = row > 21 ? 21 : row;
                sh8 Bv = *(const sh8*)&h1[row][ic0 + quad*8];
                acc[j] = __builtin_amdgcn_mfma_f32_16x16x32_bf16(A, Bv, acc[j], 0, 0, 0);
            }
        }
        #pragma unroll
        for (int j = 0; j < 2; ++j) {
            int q = 2 + 16*j + nlo;
            if (q < 20) {
                int gq = l0 - 3 + q;
                bool ok = (gq >= 0) && (gq < L);
                #pragma unroll
                for (int reg = 0; reg < 4; ++reg) {
                    int oc = wave*16 + quad*4 + reg;
                    h2[q][oc] = ok ? f2b(gelu(acc[j][reg] + kb2[oc])) : (u16)0;
                }
            }
        }
    }
    __syncthreads();

    // conv3 rows [3,19) + ecloss
    f4 acc[4];
    #pragma unroll
    for (int mf = 0; mf < 4; ++mf) acc[mf] = f4{0.f,0.f,0.f,0.f};
    {
        const sh8* w3 = (const sh8*)wp3;
        #pragma unroll
        for (int c = 0; c < 6; ++c) {
            int kk = c >> 1, ic0 = (c & 1) << 5;
            int row = 2 + nlo + kk;
            sh8 Bv = *(const sh8*)&h2[row][ic0 + quad*8];
            #pragma unroll
            for (int mf = 0; mf < 4; ++mf) {
                sh8 A = w3[(c*16 + wave*4 + mf)*64 + lane];
                acc[mf] = __builtin_amdgcn_mfma_f32_16x16x32_bf16(A, Bv, acc[mf], 0, 0, 0);
            }
        }
    }
    {
        int gp = l0 + nlo;
        double s = 0.0;
        #pragma unroll
        for (int mf = 0; mf < 4; ++mf)
            #pragma unroll
            for (int reg = 0; reg < 4; ++reg) {
                int oc = (wave*4 + mf)*16 + quad*4 + reg;
                float dx = acc[mf][reg] + kb3[oc];
                s += (double)stacked[((size_t)b*CS + oc)*L + gp] * (double)dx;
            }
        #pragma unroll
        for (int off = 32; off > 0; off >>= 1) s += __shfl_down(s, off, 64);
        if (lane == 0) sred[wave] = s;
        __syncthreads();
        if (tid == 0) atomicAdd(&inner[b], sred[0] + sred[1] + sred[2] + sred[3]);
    }
}

// ---------- wavelet part ----------
__global__ __launch_bounds__(256) void rowmax_k(const float* __restrict__ a, float* __restrict__ bm) {
    __shared__ float red[256];
    int row = blockIdx.x;
    const float* p = a + (size_t)row * L;
    float m = -1e30f;
    for (int t = threadIdx.x; t < L; t += 256) m = fmaxf(m, p[t]);
    red[threadIdx.x] = m;
    __syncthreads();
    for (int s = 128; s > 0; s >>= 1) {
        if (threadIdx.x < s) red[threadIdx.x] = fmaxf(red[threadIdx.x], red[threadIdx.x + s]);
        __syncthreads();
    }
    if (threadIdx.x == 0) bm[row] = red[0];
}

__global__ __launch_bounds__(256) void mlp_k(const float* __restrict__ bm,
    const float* __restrict__ sw1, const float* __restrict__ sb1,
    const float* __restrict__ sw2, const float* __restrict__ sb2,
    const float* __restrict__ sw3, const float* __restrict__ sb3,
    float* __restrict__ filt) {
    __shared__ float m[8][64], f1[8][32], f2[8][32], raw[8][16], nrm[8][2];
    int tid = threadIdx.x;
    for (int i = tid; i < 512; i += 256) m[i >> 6][i & 63] = bm[i];
    __syncthreads();
    {
        int b = tid >> 5, h = tid & 31;
        float s = sb1[h];
        for (int c = 0; c < 64; ++c) s += m[b][c] * sw1[h*64+c];
        f1[b][h] = gelu(s);
    }
    __syncthreads();
    {
        int b = tid >> 5, h = tid & 31;
        float s = sb2[h];
        for (int k = 0; k < 32; ++k) s += f1[b][k] * sw2[h*32+k];
        f2[b][h] = gelu(s);
    }
    __syncthreads();
    if (tid < 128) {
        int b = tid >> 4, j = tid & 15;
        float s = sb3[j];
        for (int k = 0; k < 32; ++k) s += f2[b][k] * sw3[j*32+k];
        raw[b][j] = s;
    }
    __syncthreads();
    if (tid < 16) {
        int b = tid >> 1, half = tid & 1;
        float s = 0.f;
        for (int j = 0; j < 8; ++j) { float v = raw[b][half*8+j]; s += v*v; }
        nrm[b][half] = sqrtf(s);
    }
    __syncthreads();
    if (tid < 16) {
        int half = tid >> 3;
        float s = 0.f;
        for (int b = 0; b < 8; ++b) s += raw[b][tid] / nrm[b][half];
        filt[tid] = s * 0.125f;
    }
}

__global__ __launch_bounds__(256) void wconv_k(const float* __restrict__ ap,
    const float* __restrict__ filt, float* __restrict__ apOut,
    float* __restrict__ stacked, int lev) {
    __shared__ float f[16];
    if (threadIdx.x < 16) f[threadIdx.x] = filt[threadIdx.x];
    __syncthreads();
    size_t idx = (size_t)blockIdx.x * 256 + threadIdx.x;
    int l = (int)(idx & 2047);
    size_t bc = idx >> 11;
    int c = (int)(bc & 63), b = (int)(bc >> 6);
    const float* row = ap + (bc << 11);
    float lo = 0.f, hi = 0.f;
    #pragma unroll
    for (int k = 0; k < 8; ++k) {
        int mI = l + k - 3;
        mI = mI < 0 ? -mI : (mI >= L ? 2*L - 2 - mI : mI);
        float v = row[mI];
        lo += v * f[k];
        hi += v * f[8+k];
    }
    apOut[idx] = lo;
    stacked[((size_t)b * CS + (size_t)(lev+1) * 64 + c) * L + l] = hi;
}

__global__ __launch_bounds__(256) void copyx_k(const float* __restrict__ x, float* __restrict__ st) {
    size_t i = (size_t)blockIdx.x * 256 + threadIdx.x;
    size_t b = i >> 17, rem = i & 131071;
    st[b * ((size_t)CS*L) + rem] = x[i];
}

// stacked fp32 [b][c][l] -> ytr fp32 [b][l][c] + yb bf16 [b][l][c]
__global__ __launch_bounds__(256) void tinit_k(const float* __restrict__ st,
        float* __restrict__ ytr, u16* __restrict__ yb) {
    __shared__ float t[64][65];
    const int tid = threadIdx.x;
    const int l0 = blockIdx.x * 64, c0 = blockIdx.y * 64, b = blockIdx.z;
    #pragma unroll
    for (int k = 0; k < 16; ++k) {
        int c = k * 4 + (tid >> 6), l = tid & 63;
        t[c][l] = st[((size_t)b*CS + c0 + c) * L + l0 + l];
    }
    __syncthreads();
    #pragma unroll
    for (int k = 0; k < 16; ++k) {
        int p = k * 4 + (tid >> 6), ch = tid & 63;
        float v = t[ch][p];
        size_t ta = ((size_t)b * L + l0 + p) * 256 + c0 + ch;
        ytr[ta] = v;
        yb[ta] = f2b(v);
    }
}

__global__ void ecfin_k(const double* __restrict__ inner, float* __restrict__ out) {
    double s = 0.0;
    for (int b = 0; b < 8; ++b) s += inner[b] * inner[b];
    out[BCSL] = (float)(s / 8.0);
}

extern "C" void kernel_launch(void* const* d_in, const int* in_sizes, int n_in,
                              void* d_out, int out_size, void* d_ws, size_t ws_size,
                              hipStream_t stream) {
    const float* x   = (const float*)d_in[0];
    const float* sw1 = (const float*)d_in[1];
    const float* sb1 = (const float*)d_in[2];
    const float* sw2 = (const float*)d_in[3];
    const float* sb2 = (const float*)d_in[4];
    const float* sw3 = (const float*)d_in[5];
    const float* sb3 = (const float*)d_in[6];
    const float* tw1 = (const float*)d_in[7];
    const float* tb1 = (const float*)d_in[8];
    const float* tw2 = (const float*)d_in[9];
    const float* tb2 = (const float*)d_in[10];
    const float* cw  = (const float*)d_in[11];
    const float* cb  = (const float*)d_in[12];
    const float* k1  = (const float*)d_in[13];
    const float* kb1 = (const float*)d_in[14];
    const float* k2  = (const float*)d_in[15];
    const float* kb2 = (const float*)d_in[16];
    const float* k3  = (const float*)d_in[17];
    const float* kb3 = (const float*)d_in[18];
    float* out = (float*)d_out;

    char* cur = (char*)d_ws;
    auto alloc = [&](size_t bytes) { void* p = cur; cur += (bytes + 255) & ~(size_t)255; return p; };
    float* stacked = (float*)alloc(BCSL * 4);
    float* ytr     = (float*)alloc(BCSL * 4);
    u16*   yb0     = (u16*)  alloc(BCSL * 2);
    u16*   yb1     = (u16*)  alloc(BCSL * 2);
    float* wsA     = (float*)alloc(BCL * 4);
    float* wsB     = (float*)alloc(BCL * 4);
    float* cond  = (float*)alloc(3200 * 4);
    float* bmax  = (float*)alloc(512 * 4);
    float* filt  = (float*)alloc(16 * 4);
    double* inner = (double*)alloc(8 * 8);
    u16* wp1 = (u16*)alloc(49152 * 2);
    u16* wp2 = (u16*)alloc(12288 * 2);
    u16* wp3 = (u16*)alloc(49152 * 2);

    hipMemsetAsync(inner, 0, 8 * sizeof(double), stream);

    prep_k<<<192, 256, 0, stream>>>(k1, wp1, CS, C);
    prep_k<<<48,  256, 0, stream>>>(k2, wp2, C,  C);
    prep_k<<<192, 256, 0, stream>>>(k3, wp3, C,  CS);
    cond25_k<<<25, 128, 0, stream>>>(tw1, tb1, tw2, tb2, cw, cb, cond);

    // wavelet decomposition
    copyx_k<<<4096, 256, 0, stream>>>(x, stacked);
    const float* apIn = x;
    float* apBuf[2] = {wsA, wsB};
    for (int lev = 0; lev < 3; ++lev) {
        rowmax_k<<<512, 256, 0, stream>>>(apIn, bmax);
        mlp_k<<<1, 256, 0, stream>>>(bmax, sw1, sb1, sw2, sb2, sw3, sb3, filt);
        float* apOut = apBuf[lev & 1];
        wconv_k<<<4096, 256, 0, stream>>>(apIn, filt, apOut, stacked, lev);
        apIn = apOut;
    }
    tinit_k<<<dim3(32, 4, 8), 256, 0, stream>>>(stacked, ytr, yb0);

    // RK45: one fused kernel per step; yb double-buffered
    dim3 cg(128, 8);
    rkstep_k<0><<<cg, 256, 0, stream>>>(wp1, kb1, wp2, kb2, wp3, kb3, cond,
                                        ytr, yb0, yb1, nullptr);
    rkstep_k<1><<<cg, 256, 0, stream>>>(wp1, kb1, wp2, kb2, wp3, kb3, cond,
                                        ytr, yb1, yb0, nullptr);
    rkstep_k<2><<<cg, 256, 0, stream>>>(wp1, kb1, wp2, kb2, wp3, kb3, cond,
                                        ytr, yb0, yb1, nullptr);
    rkstep_k<3><<<cg, 256, 0, stream>>>(wp1, kb1, wp2, kb2, wp3, kb3, cond,
                                        ytr, yb1, yb0, out);

    // dx = ode_f(1.0, y) + ecloss
    dxec_k<<<cg, 256, 0, stream>>>(yb0, wp1, kb1, wp2, kb2, wp3, kb3, cond,
                                   stacked, inner);
    ecfin_k<<<1, 1, 0, stream>>>(inner, out);
}

// Round 9
// 725.456 us; speedup vs baseline: 1.7023x; 1.7023x over previous
//
#include <hip/hip_runtime.h>
#include <math.h>

#define B 8
#define C 64
#define L 2048
#define CS 256
#define BCL  (B*C*L)    // 1048576
#define BCSL (B*CS*L)   // 4194304
#define HS 0.25f

typedef unsigned short u16;
typedef unsigned int   u32;
typedef __attribute__((ext_vector_type(8))) short sh8;
typedef __attribute__((ext_vector_type(4))) float f4;
typedef __attribute__((ext_vector_type(8))) unsigned short us8;
typedef __attribute__((ext_vector_type(4))) unsigned short us4;

__device__ __forceinline__ float gelu(float x) {
    return 0.5f * x * (1.0f + erff(x * 0.70710678118654752440f));
}
__device__ __forceinline__ u16 f2b(float f) {
    u32 u = __float_as_uint(f);
    u32 r = u + 0x7FFFu + ((u >> 16) & 1u);
    return (u16)(r >> 16);
}
__device__ __forceinline__ float b2f(u16 h) {
    return __uint_as_float(((u32)h) << 16);
}

struct ComboB { const u16* p[6]; float c[6]; };

// ---------- weight prep: fp32 [oc][ic][k] -> bf16 A-frag order ----------
__global__ __launch_bounds__(256) void prep_k(const float* __restrict__ w,
        u16* __restrict__ dst, int IC, int OC) {
    int idx = blockIdx.x * 256 + threadIdx.x;
    int OCG = OC >> 4;
    int j = idx & 7, lane = (idx >> 3) & 63, t = idx >> 9;
    int ocg = t % OCG, c = t / OCG;
    int oc = ocg * 16 + (lane & 15);
    int K = c * 32 + ((lane >> 4) & 3) * 8 + j;
    int kk = K / IC, ic = K % IC;
    dst[idx] = f2b(w[((size_t)oc * IC + ic) * 3 + kk]);
}

// ---------- all 25 cond vectors ----------
__global__ void cond25_k(const float* __restrict__ tw1, const float* __restrict__ tb1,
                         const float* __restrict__ tw2, const float* __restrict__ tb2,
                         const float* __restrict__ cw, const float* __restrict__ cb,
                         float* __restrict__ condall) {
    __shared__ float te1[16], te2[16];
    int tix = blockIdx.x;
    int tid = threadIdx.x;
    double add[6] = {0.0, 0.25/5.0, 3.0*0.25/10.0, 4.0*0.25/5.0, 8.0*0.25/9.0, 0.25};
    float t = (tix == 24) ? 1.0f : (float)((double)(tix / 6) * 0.25 + add[tix % 6]);
    if (tid < 16) te1[tid] = gelu(t * tw1[tid] + tb1[tid]);
    __syncthreads();
    if (tid < 16) {
        float s = tb2[tid];
        for (int k = 0; k < 16; ++k) s += te1[k] * tw2[tid*16+k];
        te2[tid] = s;
    }
    __syncthreads();
    float s = cb[tid];
    for (int j = 0; j < 16; ++j) s += te2[j] * cw[tid*16+j];
    condall[tix*128 + tid] = s;
}

// ---------- fused ode_f: conv1(FiLM,GELU) -> conv2(GELU) -> conv3 ----------
// 16-position tiles, grid (128, 8). Inputs bf16 transposed [b][pos][ch].
// ytr is fp32 TRANSPOSED [b][pos][ch], touched only in the RK epilogue.
// Halo: input 22 pos (g0=l0-3) -> h1 20 -> h2 18 -> out 16.
// EPI: 0 = store s; 1 = ytr+yb update; 2 = yb update + permuted out; 3 = ecloss
template<int NC, int EPI>
__global__ __launch_bounds__(256) void fused_k(ComboB in,
        const u16* __restrict__ wp1, const float* __restrict__ kb1,
        const u16* __restrict__ wp2, const float* __restrict__ kb2,
        const u16* __restrict__ wp3, const float* __restrict__ kb3,
        const float* __restrict__ condall, int tix,
        u16* __restrict__ outSb,
        float* __restrict__ ytr, u16* __restrict__ yb,
        float* __restrict__ outp, const float* __restrict__ stacked,
        double* __restrict__ inner)
{
    __shared__ u16 xs1[34][264];   // rows 0..21 staged, 22..33 zero
    __shared__ u16 h1t[34][72];
    __shared__ u16 h2t[18][72];
    __shared__ u16 ypart[16][264];
    __shared__ double sred[4];
    const int tid = threadIdx.x;
    const int l0  = blockIdx.x * 16;
    const int b   = blockIdx.y;
    const int g0  = l0 - 3;

    const float cy1 = HS*(35.f/384.f), cy3 = HS*(500.f/1113.f),
                cy4 = HS*(125.f/192.f), cy5 = -HS*(2187.f/6784.f),
                cy6 = HS*(11.f/84.f);

    // zero never-written-but-read rows
    for (int i = tid; i < 12*264; i += 256) xs1[22 + i/264][i%264] = 0;
    if (tid < 144) h1t[32 + tid/72][tid%72] = 0;

    // ---- staging: 704 items, software-pipelined (2-deep) global loads ----
    {
        constexpr int ITEMS = 22 * 32;
        us8 rg[2][NC];
        // prologue: load iteration 0
        {
            int idx = tid;
            if (idx < ITEMS) {
                int r = idx >> 5, c8 = idx & 31;
                int gl = g0 + r;
                if (gl >= 0 && gl < L) {
                    size_t a = ((size_t)b * L + gl) * 256 + c8 * 8;
                    #pragma unroll
                    for (int t = 0; t < NC; ++t) rg[0][t] = *(const us8*)(in.p[t] + a);
                }
            }
        }
        #pragma unroll
        for (int it = 0; it < 3; ++it) {
            // prefetch next iteration's loads
            if (it < 2) {
                int idx = (it + 1) * 256 + tid;
                if (idx < ITEMS) {
                    int r = idx >> 5, c8 = idx & 31;
                    int gl = g0 + r;
                    if (gl >= 0 && gl < L) {
                        size_t a = ((size_t)b * L + gl) * 256 + c8 * 8;
                        #pragma unroll
                        for (int t = 0; t < NC; ++t)
                            rg[(it + 1) & 1][t] = *(const us8*)(in.p[t] + a);
                    }
                }
            }
            // process current iteration
            int idx = it * 256 + tid;
            if (idx < ITEMS) {
                int r = idx >> 5, c8 = idx & 31;
                int gl = g0 + r;
                us8 val;
                if (gl >= 0 && gl < L) {
                    us8* R = rg[it & 1];
                    if (NC == 1) {
                        val = R[0];
                    } else {
                        float f[8], yp[8];
                        #pragma unroll
                        for (int j = 0; j < 8; ++j) { f[j] = b2f(R[0][j]); yp[j] = 0.f; }
                        #pragma unroll
                        for (int t = 1; t < NC; ++t) {
                            #pragma unroll
                            for (int j = 0; j < 8; ++j) {
                                float bv = b2f(R[t][j]);
                                f[j] += in.c[t] * bv;
                                if ((EPI == 1 || EPI == 2) && (t == 1 || t == 3 || t == 4 || t == 5)) {
                                    float cy = (t == 1) ? cy1 : (t == 3) ? cy3 : (t == 4) ? cy4 : cy5;
                                    yp[j] += cy * bv;
                                }
                            }
                        }
                        #pragma unroll
                        for (int j = 0; j < 8; ++j) val[j] = f2b(f[j]);
                        if ((EPI == 1 || EPI == 2) && r >= 3 && r < 19) {
                            us8 ypk;
                            #pragma unroll
                            for (int j = 0; j < 8; ++j) ypk[j] = f2b(yp[j]);
                            *(us8*)&ypart[r - 3][c8 * 8] = ypk;
                        }
                    }
                } else {
                    #pragma unroll
                    for (int j = 0; j < 8; ++j) val[j] = 0;
                }
                *(us8*)&xs1[r][c8 * 8] = val;
            }
        }
    }
    __syncthreads();

    const int wave = tid >> 6, lane = tid & 63;
    const int nlo = lane & 15, quad = lane >> 4;

    // ---- conv1: M=16/wave, N=32, K=768 ----
    f4 a1[2];
    a1[0] = f4{0.f,0.f,0.f,0.f}; a1[1] = a1[0];
    {
        const sh8* w1 = (const sh8*)wp1;
        for (int c = 0; c < 24; ++c) {
            int kk = c >> 3, ic0 = (c & 7) << 5;
            sh8 A = w1[(c*4 + wave)*64 + lane];
            #pragma unroll
            for (int nf = 0; nf < 2; ++nf) {
                sh8 Bv = *(const sh8*)&xs1[nf*16 + nlo + kk][ic0 + quad*8];
                a1[nf] = __builtin_amdgcn_mfma_f32_16x16x32_bf16(A, Bv, a1[nf], 0, 0, 0);
            }
        }
    }
    {
        const float* cd = condall + tix*128;
        #pragma unroll
        for (int nf = 0; nf < 2; ++nf) {
            int p = nf*16 + nlo;
            int gp = l0 - 2 + p;
            bool ok = (p < 20) && (gp >= 0) && (gp < L);
            #pragma unroll
            for (int reg = 0; reg < 4; ++reg) {
                int oc = wave*16 + quad*4 + reg;
                float v = (1.f + cd[oc]) * (a1[nf][reg] + kb1[oc]) + cd[64+oc];
                h1t[p][oc] = ok ? f2b(gelu(v)) : (u16)0;
            }
        }
    }
    __syncthreads();

    // ---- conv2: M=16/wave, N=32, K=192 ----
    f4 a2[2];
    a2[0] = f4{0.f,0.f,0.f,0.f}; a2[1] = a2[0];
    {
        const sh8* w2 = (const sh8*)wp2;
        #pragma unroll
        for (int c = 0; c < 6; ++c) {
            int kk = c >> 1, ic0 = (c & 1) << 5;
            sh8 A = w2[(c*4 + wave)*64 + lane];
            #pragma unroll
            for (int nf = 0; nf < 2; ++nf) {
                sh8 Bv = *(const sh8*)&h1t[nf*16 + nlo + kk][ic0 + quad*8];
                a2[nf] = __builtin_amdgcn_mfma_f32_16x16x32_bf16(A, Bv, a2[nf], 0, 0, 0);
            }
        }
    }
    {
        #pragma unroll
        for (int nf = 0; nf < 2; ++nf) {
            int q = nf*16 + nlo;
            if (q < 18) {
                int gq = l0 - 1 + q;
                bool ok = (gq >= 0) && (gq < L);
                #pragma unroll
                for (int reg = 0; reg < 4; ++reg) {
                    int oc = wave*16 + quad*4 + reg;
                    h2t[q][oc] = ok ? f2b(gelu(a2[nf][reg] + kb2[oc])) : (u16)0;
                }
            }
        }
    }
    __syncthreads();

    // ---- conv3: M=64/wave, N=16, K=192 ----
    f4 a3[4];
    #pragma unroll
    for (int mf = 0; mf < 4; ++mf) a3[mf] = f4{0.f,0.f,0.f,0.f};
    {
        const sh8* w3 = (const sh8*)wp3;
        #pragma unroll
        for (int c = 0; c < 6; ++c) {
            int kk = c >> 1, ic0 = (c & 1) << 5;
            sh8 B0 = *(const sh8*)&h2t[nlo + kk][ic0 + quad*8];
            #pragma unroll
            for (int mf = 0; mf < 4; ++mf) {
                sh8 A = w3[(c*16 + wave*4 + mf)*64 + lane];
                a3[mf] = __builtin_amdgcn_mfma_f32_16x16x32_bf16(A, B0, a3[mf], 0, 0, 0);
            }
        }
    }

    // ---- epilogue ----
    const int pos = l0 + nlo;
    if (EPI == 3) {
        double acc = 0.0;
        #pragma unroll
        for (int mf = 0; mf < 4; ++mf)
            #pragma unroll
            for (int reg = 0; reg < 4; ++reg) {
                int oc = (wave*4 + mf)*16 + quad*4 + reg;
                size_t idx = ((size_t)b*CS + oc)*L + pos;
                float dx = a3[mf][reg] + kb3[oc];
                acc += (double)stacked[idx] * (double)dx;
            }
        #pragma unroll
        for (int off = 32; off > 0; off >>= 1) acc += __shfl_down(acc, off, 64);
        if (lane == 0) sred[wave] = acc;
        __syncthreads();
        if (tid == 0) atomicAdd(&inner[b], sred[0] + sred[1] + sred[2] + sred[3]);
    } else if (EPI == 0) {
        #pragma unroll
        for (int mf = 0; mf < 4; ++mf) {
            int baseoc = (wave*4 + mf)*16 + quad*4;
            us4 pk;
            #pragma unroll
            for (int reg = 0; reg < 4; ++reg)
                pk[reg] = f2b(a3[mf][reg] + kb3[baseoc + reg]);
            *(us4*)(outSb + ((size_t)b*L + pos)*256 + baseoc) = pk;
        }
    } else {
        #pragma unroll
        for (int mf = 0; mf < 4; ++mf) {
            int baseoc = (wave*4 + mf)*16 + quad*4;
            size_t ta = ((size_t)b*L + pos)*256 + baseoc;
            us4 yp4 = *(const us4*)&ypart[nlo][baseoc];
            f4 y4 = *(const f4*)(ytr + ta);
            us4 pk;
            f4 yo;
            #pragma unroll
            for (int reg = 0; reg < 4; ++reg) {
                int oc = baseoc + reg;
                float s6 = a3[mf][reg] + kb3[oc];
                float yv = y4[reg] + b2f(yp4[reg]) + cy6 * s6;
                yo[reg] = yv;
                pk[reg] = f2b(yv);
                if (EPI == 2) {
                    size_t oidx = (((size_t)(oc >> 6)*B + b)*64 + (oc & 63))*L + pos;
                    outp[oidx] = yv;
                }
            }
            if (EPI == 1) *(f4*)(ytr + ta) = yo;
            *(us4*)(yb + ta) = pk;
        }
    }
}

// ---------- wavelet part ----------
__global__ __launch_bounds__(256) void rowmax_k(const float* __restrict__ a, float* __restrict__ bm) {
    __shared__ float red[256];
    int row = blockIdx.x;
    const float* p = a + (size_t)row * L;
    float m = -1e30f;
    for (int t = threadIdx.x; t < L; t += 256) m = fmaxf(m, p[t]);
    red[threadIdx.x] = m;
    __syncthreads();
    for (int s = 128; s > 0; s >>= 1) {
        if (threadIdx.x < s) red[threadIdx.x] = fmaxf(red[threadIdx.x], red[threadIdx.x + s]);
        __syncthreads();
    }
    if (threadIdx.x == 0) bm[row] = red[0];
}

__global__ __launch_bounds__(256) void mlp_k(const float* __restrict__ bm,
    const float* __restrict__ sw1, const float* __restrict__ sb1,
    const float* __restrict__ sw2, const float* __restrict__ sb2,
    const float* __restrict__ sw3, const float* __restrict__ sb3,
    float* __restrict__ filt) {
    __shared__ float m[8][64], f1[8][32], f2[8][32], raw[8][16], nrm[8][2];
    int tid = threadIdx.x;
    for (int i = tid; i < 512; i += 256) m[i >> 6][i & 63] = bm[i];
    __syncthreads();
    {
        int b = tid >> 5, h = tid & 31;
        float s = sb1[h];
        for (int c = 0; c < 64; ++c) s += m[b][c] * sw1[h*64+c];
        f1[b][h] = gelu(s);
    }
    __syncthreads();
    {
        int b = tid >> 5, h = tid & 31;
        float s = sb2[h];
        for (int k = 0; k < 32; ++k) s += f1[b][k] * sw2[h*32+k];
        f2[b][h] = gelu(s);
    }
    __syncthreads();
    if (tid < 128) {
        int b = tid >> 4, j = tid & 15;
        float s = sb3[j];
        for (int k = 0; k < 32; ++k) s += f2[b][k] * sw3[j*32+k];
        raw[b][j] = s;
    }
    __syncthreads();
    if (tid < 16) {
        int b = tid >> 1, half = tid & 1;
        float s = 0.f;
        for (int j = 0; j < 8; ++j) { float v = raw[b][half*8+j]; s += v*v; }
        nrm[b][half] = sqrtf(s);
    }
    __syncthreads();
    if (tid < 16) {
        int half = tid >> 3;
        float s = 0.f;
        for (int b = 0; b < 8; ++b) s += raw[b][tid] / nrm[b][half];
        filt[tid] = s * 0.125f;
    }
}

__global__ __launch_bounds__(256) void wconv_k(const float* __restrict__ ap,
    const float* __restrict__ filt, float* __restrict__ apOut,
    float* __restrict__ stacked, int lev) {
    __shared__ float f[16];
    if (threadIdx.x < 16) f[threadIdx.x] = filt[threadIdx.x];
    __syncthreads();
    size_t idx = (size_t)blockIdx.x * 256 + threadIdx.x;
    int l = (int)(idx & 2047);
    size_t bc = idx >> 11;
    int c = (int)(bc & 63), b = (int)(bc >> 6);
    const float* row = ap + (bc << 11);
    float lo = 0.f, hi = 0.f;
    #pragma unroll
    for (int k = 0; k < 8; ++k) {
        int mI = l + k - 3;
        mI = mI < 0 ? -mI : (mI >= L ? 2*L - 2 - mI : mI);
        float v = row[mI];
        lo += v * f[k];
        hi += v * f[8+k];
    }
    apOut[idx] = lo;
    stacked[((size_t)b * CS + (size_t)(lev+1) * 64 + c) * L + l] = hi;
}

__global__ __launch_bounds__(256) void copyx_k(const float* __restrict__ x, float* __restrict__ st) {
    size_t i = (size_t)blockIdx.x * 256 + threadIdx.x;
    size_t b = i >> 17, rem = i & 131071;
    st[b * ((size_t)CS*L) + rem] = x[i];
}

// stacked fp32 [b][c][l] -> ytr fp32 [b][l][c] + yb bf16 [b][l][c]
__global__ __launch_bounds__(256) void tinit_k(const float* __restrict__ st,
        float* __restrict__ ytr, u16* __restrict__ yb) {
    __shared__ float t[64][65];
    const int tid = threadIdx.x;
    const int l0 = blockIdx.x * 64, c0 = blockIdx.y * 64, b = blockIdx.z;
    #pragma unroll
    for (int k = 0; k < 16; ++k) {
        int c = k * 4 + (tid >> 6), l = tid & 63;
        t[c][l] = st[((size_t)b*CS + c0 + c) * L + l0 + l];
    }
    __syncthreads();
    #pragma unroll
    for (int k = 0; k < 16; ++k) {
        int p = k * 4 + (tid >> 6), ch = tid & 63;
        float v = t[ch][p];
        size_t ta = ((size_t)b * L + l0 + p) * 256 + c0 + ch;
        ytr[ta] = v;
        yb[ta] = f2b(v);
    }
}

__global__ void ecfin_k(const double* __restrict__ inner, float* __restrict__ out) {
    double s = 0.0;
    for (int b = 0; b < 8; ++b) s += inner[b] * inner[b];
    out[BCSL] = (float)(s / 8.0);
}

extern "C" void kernel_launch(void* const* d_in, const int* in_sizes, int n_in,
                              void* d_out, int out_size, void* d_ws, size_t ws_size,
                              hipStream_t stream) {
    const float* x   = (const float*)d_in[0];
    const float* sw1 = (const float*)d_in[1];
    const float* sb1 = (const float*)d_in[2];
    const float* sw2 = (const float*)d_in[3];
    const float* sb2 = (const float*)d_in[4];
    const float* sw3 = (const float*)d_in[5];
    const float* sb3 = (const float*)d_in[6];
    const float* tw1 = (const float*)d_in[7];
    const float* tb1 = (const float*)d_in[8];
    const float* tw2 = (const float*)d_in[9];
    const float* tb2 = (const float*)d_in[10];
    const float* cw  = (const float*)d_in[11];
    const float* cb  = (const float*)d_in[12];
    const float* k1  = (const float*)d_in[13];
    const float* kb1 = (const float*)d_in[14];
    const float* k2  = (const float*)d_in[15];
    const float* kb2 = (const float*)d_in[16];
    const float* k3  = (const float*)d_in[17];
    const float* kb3 = (const float*)d_in[18];
    float* out = (float*)d_out;

    char* cur = (char*)d_ws;
    auto alloc = [&](size_t bytes) { void* p = cur; cur += (bytes + 255) & ~(size_t)255; return p; };
    float* stacked = (float*)alloc(BCSL * 4);
    float* ytr     = (float*)alloc(BCSL * 4);
    u16*   yb      = (u16*)  alloc(BCSL * 2);
    u16*   sbuf[5];
    for (int i = 0; i < 5; ++i) sbuf[i] = (u16*)alloc(BCSL * 2);
    float* cond  = (float*)alloc(3200 * 4);
    float* bmax  = (float*)alloc(512 * 4);
    float* filt  = (float*)alloc(16 * 4);
    double* inner = (double*)alloc(8 * 8);
    u16* wp1 = (u16*)alloc(49152 * 2);
    u16* wp2 = (u16*)alloc(12288 * 2);
    u16* wp3 = (u16*)alloc(49152 * 2);

    u16 *s1b = sbuf[0], *s2b = sbuf[1], *s3b = sbuf[2], *s4b = sbuf[3], *s5b = sbuf[4];

    hipMemsetAsync(inner, 0, 8 * sizeof(double), stream);

    prep_k<<<192, 256, 0, stream>>>(k1, wp1, CS, C);
    prep_k<<<48,  256, 0, stream>>>(k2, wp2, C,  C);
    prep_k<<<192, 256, 0, stream>>>(k3, wp3, C,  CS);
    cond25_k<<<25, 128, 0, stream>>>(tw1, tb1, tw2, tb2, cw, cb, cond);

    // wavelet decomposition (s1b/s2b regions as fp32 scratch)
    copyx_k<<<4096, 256, 0, stream>>>(x, stacked);
    const float* apIn = x;
    float* apBuf[2] = {(float*)s1b, (float*)s2b};
    for (int lev = 0; lev < 3; ++lev) {
        rowmax_k<<<512, 256, 0, stream>>>(apIn, bmax);
        mlp_k<<<1, 256, 0, stream>>>(bmax, sw1, sb1, sw2, sb2, sw3, sb3, filt);
        float* apOut = apBuf[lev & 1];
        wconv_k<<<4096, 256, 0, stream>>>(apIn, filt, apOut, stacked, lev);
        apIn = apOut;
    }
    tinit_k<<<dim3(32, 4, 8), 256, 0, stream>>>(stacked, ytr, yb);

    const float hs = HS;
    dim3 cg(128, 8);
    #define LAUNCH(NC, EPI, CIN, TIX, OUTSB, OUTP, STK) \
        fused_k<NC, EPI><<<cg, 256, 0, stream>>>(CIN, wp1, kb1, wp2, kb2, wp3, kb3, \
            cond, TIX, OUTSB, ytr, yb, OUTP, STK, inner)

    for (int i = 0; i < 4; ++i) {
        ComboB cA{}; cA.p[0] = yb;
        LAUNCH(1, 0, cA, i*6+0, s1b, nullptr, nullptr);

        ComboB cB{}; cB.p[0] = yb; cB.p[1] = s1b; cB.c[1] = hs*(1.f/5.f);
        LAUNCH(2, 0, cB, i*6+1, s2b, nullptr, nullptr);

        ComboB cC{}; cC.p[0] = yb;
        cC.p[1] = s1b; cC.c[1] = hs*(3.f/40.f);
        cC.p[2] = s2b; cC.c[2] = hs*(9.f/40.f);
        LAUNCH(3, 0, cC, i*6+2, s3b, nullptr, nullptr);

        ComboB cD{}; cD.p[0] = yb;
        cD.p[1] = s1b; cD.c[1] = hs*(44.f/45.f);
        cD.p[2] = s2b; cD.c[2] = -hs*(56.f/15.f);
        cD.p[3] = s3b; cD.c[3] = hs*(32.f/9.f);
        LAUNCH(4, 0, cD, i*6+3, s4b, nullptr, nullptr);

        ComboB cE{}; cE.p[0] = yb;
        cE.p[1] = s1b; cE.c[1] = hs*(19372.f/6561.f);
        cE.p[2] = s2b; cE.c[2] = -hs*(25360.f/2187.f);
        cE.p[3] = s3b; cE.c[3] = hs*(64448.f/6561.f);
        cE.p[4] = s4b; cE.c[4] = -hs*(212.f/729.f);
        LAUNCH(5, 0, cE, i*6+4, s5b, nullptr, nullptr);

        ComboB cF{}; cF.p[0] = yb;
        cF.p[1] = s1b; cF.c[1] = hs*(9017.f/3168.f);
        cF.p[2] = s2b; cF.c[2] = -hs*(355.f/33.f);
        cF.p[3] = s3b; cF.c[3] = hs*(46732.f/5247.f);
        cF.p[4] = s4b; cF.c[4] = hs*(49.f/176.f);
        cF.p[5] = s5b; cF.c[5] = -hs*(5103.f/18656.f);
        if (i < 3) {
            LAUNCH(6, 1, cF, i*6+5, nullptr, nullptr, nullptr);   // ytr + yb update
        } else {
            LAUNCH(6, 2, cF, i*6+5, nullptr, out, nullptr);       // yb update + gather
        }
    }

    // dx = ode_f(1.0, yb), ecloss fused (dx never stored)
    ComboB cZ{}; cZ.p[0] = yb;
    LAUNCH(1, 3, cZ, 24, nullptr, nullptr, stacked);
    ecfin_k<<<1, 1, 0, stream>>>(inner, out);
    #undef LAUNCH
}